// Round 1
// baseline (283.153 us; speedup 1.0000x reference)
//
#include <hip/hip_runtime.h>

#define MARGIN 0.3f
#define EPS 1e-6f

constexpr int B = 64, N = 512, D = 512;

// ws layout: [0] float sum, [1] int count
__global__ void tl_init(float* wsum, int* wcnt) {
    if (threadIdx.x == 0) { *wsum = 0.0f; *wcnt = 0; }
}

__global__ __launch_bounds__(256) void tl_main(const float* __restrict__ feats,
                                               const int* __restrict__ ids,
                                               float* __restrict__ wsum,
                                               int* __restrict__ wcnt) {
    __shared__ float s_sum;
    __shared__ int s_cnt;
    if (threadIdx.x == 0) { s_sum = 0.0f; s_cnt = 0; }
    __syncthreads();

    const int lane = threadIdx.x & 63;
    const int wave = threadIdx.x >> 6;          // 4 waves/block, 1 anchor/wave
    const int anchor = (blockIdx.x << 2) + wave; // 0 .. B*N-1
    const int b = anchor >> 9;                   // /N
    const int i = anchor & (N - 1);

    const int* __restrict__ bid = ids + b * N;
    const int my_id = bid[i];

    // Scan ids: first pos j (same id, j!=i, valid), first neg j (diff id, valid),
    // and count of valid ids in this batch. j increases per lane -> first match is min.
    int posj = N, negj = N, vcnt = 0;
    #pragma unroll
    for (int k = 0; k < N / 64; ++k) {
        const int j = lane + 64 * k;
        const int idj = bid[j];
        if (idj >= 0) {
            ++vcnt;
            if (idj == my_id) {
                if (j != i && j < posj) posj = j;
            } else {
                if (j < negj) negj = j;
            }
        }
    }
    #pragma unroll
    for (int off = 32; off >= 1; off >>= 1) {
        posj = min(posj, __shfl_xor(posj, off));
        negj = min(negj, __shfl_xor(negj, off));
        vcnt += __shfl_xor(vcnt, off);
    }

    const bool ok = (my_id >= 0) && (posj < N) && (negj < N) && (vcnt >= 2);

    float per = 0.0f;
    if (ok) {  // wave-uniform branch, no divergence inside
        const size_t rowA = ((size_t)b * N + i) * D;
        const size_t rowP = ((size_t)b * N + posj) * D;
        const size_t rowN = ((size_t)b * N + negj) * D;
        // lane covers floats [lane*8, lane*8+8) via two float4 loads (16B/lane)
        const float4* fa = (const float4*)(feats + rowA) + lane * 2;
        const float4* fp = (const float4*)(feats + rowP) + lane * 2;
        const float4* fn = (const float4*)(feats + rowN) + lane * 2;
        float sap = 0.0f, san = 0.0f;
        #pragma unroll
        for (int k = 0; k < 2; ++k) {
            const float4 a = fa[k];
            const float4 p = fp[k];
            const float4 n = fn[k];
            float d;
            d = a.x - p.x + EPS; sap += d * d;
            d = a.y - p.y + EPS; sap += d * d;
            d = a.z - p.z + EPS; sap += d * d;
            d = a.w - p.w + EPS; sap += d * d;
            d = a.x - n.x + EPS; san += d * d;
            d = a.y - n.y + EPS; san += d * d;
            d = a.z - n.z + EPS; san += d * d;
            d = a.w - n.w + EPS; san += d * d;
        }
        #pragma unroll
        for (int off = 32; off >= 1; off >>= 1) {
            sap += __shfl_xor(sap, off);
            san += __shfl_xor(san, off);
        }
        per = fmaxf(sqrtf(sap) - sqrtf(san) + MARGIN, 0.0f);
        if (lane == 0) {
            atomicAdd(&s_sum, per);
            atomicAdd(&s_cnt, 1);
        }
    }
    __syncthreads();
    if (threadIdx.x == 0 && s_cnt > 0) {
        atomicAdd(wsum, s_sum);
        atomicAdd(wcnt, s_cnt);
    }
}

__global__ void tl_finalize(const float* __restrict__ wsum,
                            const int* __restrict__ wcnt,
                            float* __restrict__ out) {
    if (threadIdx.x == 0) {
        const int c = *wcnt;
        const float loss = (c > 0) ? (*wsum / (float)c) : 0.0f;
        out[0] = loss;   // tracking_loss = triplet + id
        out[1] = loss;   // loss_triplet
        out[2] = 0.0f;   // loss_id
    }
}

extern "C" void kernel_launch(void* const* d_in, const int* in_sizes, int n_in,
                              void* d_out, int out_size, void* d_ws, size_t ws_size,
                              hipStream_t stream) {
    const float* feats = (const float*)d_in[0];  // (B,N,D) fp32
    const int* ids = (const int*)d_in[1];        // (B,N) int32
    float* out = (float*)d_out;                  // 3 fp32 scalars

    float* wsum = (float*)d_ws;
    int* wcnt = (int*)((char*)d_ws + sizeof(float));

    tl_init<<<1, 64, 0, stream>>>(wsum, wcnt);
    tl_main<<<(B * N) / 4, 256, 0, stream>>>(feats, ids, wsum, wcnt);
    tl_finalize<<<1, 64, 0, stream>>>(wsum, wcnt, out);
}

// Round 2
// 104.992 us; speedup vs baseline: 2.6969x; 2.6969x over previous
//
#include <hip/hip_runtime.h>

#define MARGIN 0.3f
#define EPS 1e-6f

constexpr int B = 64, N = 512, D = 512;
constexpr int NIDS = 32;          // track ids are in [-1, 32)
constexpr int BLOCKS = 512;       // 8 blocks per batch
constexpr int THREADS = 512;      // 8 waves per block
constexpr int WAVES = THREADS / 64;
constexpr int ANCH_PER_BLOCK = N / 8;              // 64
constexpr int ANCH_PER_WAVE = ANCH_PER_BLOCK / WAVES; // 8

// ws layout: float psum[512]; float pcnt[512]  (4 KB)
__global__ __launch_bounds__(THREADS) void tl_main(const float* __restrict__ feats,
                                                   const int* __restrict__ ids,
                                                   float* __restrict__ psum,
                                                   float* __restrict__ pcnt) {
    __shared__ int s_ids[N];
    __shared__ int s_first[NIDS], s_second[NIDS];
    __shared__ int s_j0, s_jdiff, s_vcnt;
    __shared__ float s_wsum[WAVES];
    __shared__ int s_wcnt[WAVES];

    const int t = threadIdx.x;
    const int b = blockIdx.x >> 3;                 // batch
    const int seg = (blockIdx.x & 7) * ANCH_PER_BLOCK;
    const int* __restrict__ bid = ids + b * N;

    if (t < NIDS) { s_first[t] = N; s_second[t] = N; }
    if (t == 0) { s_j0 = N; s_jdiff = N; s_vcnt = 0; }
    __syncthreads();

    // Load ids to LDS + pass 1: first occurrence per id, first valid overall, valid count.
    {
        const int v = bid[t];                      // THREADS == N, one each
        s_ids[t] = v;
        if (v >= 0) {
            atomicMin(&s_first[v], t);
            atomicMin(&s_j0, t);
            atomicAdd(&s_vcnt, 1);
        }
    }
    __syncthreads();
    const int id0 = (s_j0 < N) ? s_ids[s_j0] : -2; // id of first valid (or sentinel)
    // Pass 2: second occurrence per id; first valid with a different id than id0.
    {
        const int v = s_ids[t];
        if (v >= 0) {
            if (s_first[v] != t) atomicMin(&s_second[v], t);
            if (v != id0) atomicMin(&s_jdiff, t);
        }
    }
    __syncthreads();

    const int lane = t & 63;
    const int wave = t >> 6;
    const float* __restrict__ bf = feats + (size_t)b * N * D;
    const int vcnt = s_vcnt;
    const int j0 = s_j0, jdiff = s_jdiff;

    float wsum = 0.0f;
    int wcnt = 0;

    #pragma unroll
    for (int k = 0; k < ANCH_PER_WAVE; ++k) {
        const int i = seg + wave * ANCH_PER_WAVE + k;   // anchor index (wave-uniform)
        const int v = s_ids[i];
        bool ok = false;
        int posj = 0, negj = 0;
        if (v >= 0 && vcnt >= 2) {
            // pos = first j with same id and j != i (argmax of bool mask = first True)
            posj = (s_first[v] != i) ? s_first[v] : s_second[v];
            // neg = first valid j with different id
            negj = (id0 != v) ? j0 : jdiff;
            ok = (posj < N) && (negj < N);
        }
        if (ok) {  // wave-uniform branch
            const float4* fa = (const float4*)(bf + (size_t)i * D) + lane * 2;
            const float4* fp = (const float4*)(bf + (size_t)posj * D) + lane * 2;
            const float4* fn = (const float4*)(bf + (size_t)negj * D) + lane * 2;
            float sap = 0.0f, san = 0.0f;
            #pragma unroll
            for (int q = 0; q < 2; ++q) {
                const float4 a = fa[q];
                const float4 p = fp[q];
                const float4 n = fn[q];
                float d;
                d = a.x - p.x + EPS; sap += d * d;
                d = a.y - p.y + EPS; sap += d * d;
                d = a.z - p.z + EPS; sap += d * d;
                d = a.w - p.w + EPS; sap += d * d;
                d = a.x - n.x + EPS; san += d * d;
                d = a.y - n.y + EPS; san += d * d;
                d = a.z - n.z + EPS; san += d * d;
                d = a.w - n.w + EPS; san += d * d;
            }
            #pragma unroll
            for (int off = 32; off >= 1; off >>= 1) {
                sap += __shfl_xor(sap, off);
                san += __shfl_xor(san, off);
            }
            wsum += fmaxf(sqrtf(sap) - sqrtf(san) + MARGIN, 0.0f);
            ++wcnt;
        }
    }

    if (lane == 0) { s_wsum[wave] = wsum; s_wcnt[wave] = wcnt; }
    __syncthreads();
    if (t == 0) {
        float s = 0.0f; int c = 0;
        #pragma unroll
        for (int w = 0; w < WAVES; ++w) { s += s_wsum[w]; c += s_wcnt[w]; }
        psum[blockIdx.x] = s;
        pcnt[blockIdx.x] = (float)c;
    }
}

__global__ __launch_bounds__(256) void tl_finalize(const float* __restrict__ psum,
                                                   const float* __restrict__ pcnt,
                                                   float* __restrict__ out) {
    __shared__ float s_s[4], s_c[4];
    const int t = threadIdx.x;
    float s = 0.0f, c = 0.0f;
    for (int k = t; k < BLOCKS; k += 256) { s += psum[k]; c += pcnt[k]; }
    #pragma unroll
    for (int off = 32; off >= 1; off >>= 1) {
        s += __shfl_xor(s, off);
        c += __shfl_xor(c, off);
    }
    if ((t & 63) == 0) { s_s[t >> 6] = s; s_c[t >> 6] = c; }
    __syncthreads();
    if (t == 0) {
        const float S = s_s[0] + s_s[1] + s_s[2] + s_s[3];
        const float C = s_c[0] + s_c[1] + s_c[2] + s_c[3];
        const float loss = (C > 0.0f) ? (S / C) : 0.0f;
        out[0] = loss;   // tracking_loss = triplet + id(=0)
        out[1] = loss;   // loss_triplet
        out[2] = 0.0f;   // loss_id
    }
}

extern "C" void kernel_launch(void* const* d_in, const int* in_sizes, int n_in,
                              void* d_out, int out_size, void* d_ws, size_t ws_size,
                              hipStream_t stream) {
    const float* feats = (const float*)d_in[0];  // (B,N,D) fp32
    const int* ids = (const int*)d_in[1];        // (B,N) int32
    float* out = (float*)d_out;                  // 3 fp32 scalars

    float* psum = (float*)d_ws;                  // 512 floats
    float* pcnt = psum + BLOCKS;                 // 512 floats

    tl_main<<<BLOCKS, THREADS, 0, stream>>>(feats, ids, psum, pcnt);
    tl_finalize<<<1, 256, 0, stream>>>(psum, pcnt, out);
}

// Round 3
// 104.864 us; speedup vs baseline: 2.7002x; 1.0012x over previous
//
#include <hip/hip_runtime.h>

#define MARGIN 0.3f
#define EPS 1e-6f

constexpr int B = 64, N = 512, D = 512;
constexpr int NIDS = 32;          // track ids in [-1, 32)

constexpr int MB_THREADS = 256;
constexpr int MB_WAVES = MB_THREADS / 64;            // 4
constexpr int ANCH_PER_WAVE = 4;
constexpr int MB_BLOCKS = (B * N) / (MB_WAVES * ANCH_PER_WAVE); // 2048

// ws layout:
//   int2  desc[B*N]        (256 KB)  per-anchor {posj, negj}, posj=-1 -> skip
//   int2  hdr[B]           (512 B)   per-batch {j0, jdiff} (clamped to N-1)
//   float psum[MB_BLOCKS]  (8 KB)
//   float pcnt[MB_BLOCKS]  (8 KB)

__global__ __launch_bounds__(512) void tl_tables(const int* __restrict__ ids,
                                                 int2* __restrict__ desc,
                                                 int2* __restrict__ hdr) {
    __shared__ int s_ids[N];
    __shared__ int s_first[NIDS], s_second[NIDS];
    __shared__ int s_j0, s_jdiff, s_vcnt;
    const int t = threadIdx.x;
    const int b = blockIdx.x;

    if (t < NIDS) { s_first[t] = N; s_second[t] = N; }
    if (t == 0) { s_j0 = N; s_jdiff = N; s_vcnt = 0; }
    __syncthreads();

    const int v = ids[b * N + t];          // one id per thread (512 == N)
    s_ids[t] = v;
    if (v >= 0) {
        atomicMin(&s_first[v], t);
        atomicMin(&s_j0, t);
        atomicAdd(&s_vcnt, 1);
    }
    __syncthreads();
    const int id0 = (s_j0 < N) ? s_ids[s_j0] : -2;
    if (v >= 0) {
        if (s_first[v] != t) atomicMin(&s_second[v], t);  // second occurrence
        if (v != id0) atomicMin(&s_jdiff, t);             // first valid w/ id != id0
    }
    __syncthreads();

    int2 d = make_int2(-1, -1);
    if (v >= 0 && s_vcnt >= 2) {
        // argmax of bool mask = first True
        const int posj = (s_first[v] != t) ? s_first[v] : s_second[v];
        const int negj = (v != id0) ? s_j0 : s_jdiff;
        if (posj < N && negj < N) d = make_int2(posj, negj);
    }
    desc[b * N + t] = d;
    if (t == 0) hdr[b] = make_int2(min(s_j0, N - 1), min(s_jdiff, N - 1));
}

__global__ __launch_bounds__(MB_THREADS, 4) void tl_main(const float* __restrict__ feats,
                                                         const int2* __restrict__ desc,
                                                         const int2* __restrict__ hdr,
                                                         float* __restrict__ psum,
                                                         float* __restrict__ pcnt) {
    __shared__ float s_wsum[MB_WAVES];
    __shared__ int s_wcnt[MB_WAVES];

    const int t = threadIdx.x;
    const int lane = t & 63;
    const int wave = t >> 6;
    const int gw = blockIdx.x * MB_WAVES + wave;     // global wave id, 0..8191
    const int b = gw >> 7;                           // 128 waves per batch
    const int i0 = (gw & 127) * ANCH_PER_WAVE;
    const float* __restrict__ bf = feats + (size_t)b * N * D;

    // Register-cache the two negative-candidate rows of this batch.
    const int2 h = hdr[b];
    const float4* n0p = (const float4*)(bf + (size_t)h.x * D) + lane * 2;
    const float4* n1p = (const float4*)(bf + (size_t)h.y * D) + lane * 2;
    const float4 n0a = n0p[0], n0b = n0p[1];
    const float4 n1a = n1p[0], n1b = n1p[1];

    float wsum = 0.0f;
    int wcnt = 0;

    #pragma unroll
    for (int k = 0; k < ANCH_PER_WAVE; ++k) {
        const int i = i0 + k;
        const int2 d = desc[b * N + i];
        const bool ok = (d.x >= 0);
        const int pj = ok ? d.x : 0;

        const float4* fa = (const float4*)(bf + (size_t)i * D) + lane * 2;
        const float4* fp = (const float4*)(bf + (size_t)pj * D) + lane * 2;
        const float4 a0 = fa[0], a1 = fa[1];
        const float4 p0 = fp[0], p1 = fp[1];

        const bool useN0 = (d.y == h.x);
        const float4 m0 = useN0 ? n0a : n1a;
        const float4 m1 = useN0 ? n0b : n1b;

        float sap = 0.0f, san = 0.0f, dd;
        dd = a0.x - p0.x + EPS; sap += dd * dd;
        dd = a0.y - p0.y + EPS; sap += dd * dd;
        dd = a0.z - p0.z + EPS; sap += dd * dd;
        dd = a0.w - p0.w + EPS; sap += dd * dd;
        dd = a1.x - p1.x + EPS; sap += dd * dd;
        dd = a1.y - p1.y + EPS; sap += dd * dd;
        dd = a1.z - p1.z + EPS; sap += dd * dd;
        dd = a1.w - p1.w + EPS; sap += dd * dd;
        dd = a0.x - m0.x + EPS; san += dd * dd;
        dd = a0.y - m0.y + EPS; san += dd * dd;
        dd = a0.z - m0.z + EPS; san += dd * dd;
        dd = a0.w - m0.w + EPS; san += dd * dd;
        dd = a1.x - m1.x + EPS; san += dd * dd;
        dd = a1.y - m1.y + EPS; san += dd * dd;
        dd = a1.z - m1.z + EPS; san += dd * dd;
        dd = a1.w - m1.w + EPS; san += dd * dd;

        #pragma unroll
        for (int off = 32; off >= 1; off >>= 1) {
            sap += __shfl_xor(sap, off);
            san += __shfl_xor(san, off);
        }
        const float per = fmaxf(sqrtf(sap) - sqrtf(san) + MARGIN, 0.0f);
        wsum += ok ? per : 0.0f;
        wcnt += ok ? 1 : 0;
    }

    if (lane == 0) { s_wsum[wave] = wsum; s_wcnt[wave] = wcnt; }
    __syncthreads();
    if (t == 0) {
        float s = 0.0f; int c = 0;
        #pragma unroll
        for (int w = 0; w < MB_WAVES; ++w) { s += s_wsum[w]; c += s_wcnt[w]; }
        psum[blockIdx.x] = s;
        pcnt[blockIdx.x] = (float)c;
    }
}

__global__ __launch_bounds__(256) void tl_finalize(const float* __restrict__ psum,
                                                   const float* __restrict__ pcnt,
                                                   float* __restrict__ out) {
    __shared__ float s_s[4], s_c[4];
    const int t = threadIdx.x;
    float s = 0.0f, c = 0.0f;
    for (int k = t; k < MB_BLOCKS; k += 256) { s += psum[k]; c += pcnt[k]; }
    #pragma unroll
    for (int off = 32; off >= 1; off >>= 1) {
        s += __shfl_xor(s, off);
        c += __shfl_xor(c, off);
    }
    if ((t & 63) == 0) { s_s[t >> 6] = s; s_c[t >> 6] = c; }
    __syncthreads();
    if (t == 0) {
        const float S = s_s[0] + s_s[1] + s_s[2] + s_s[3];
        const float C = s_c[0] + s_c[1] + s_c[2] + s_c[3];
        const float loss = (C > 0.0f) ? (S / C) : 0.0f;
        out[0] = loss;   // tracking_loss = triplet + id(=0)
        out[1] = loss;   // loss_triplet
        out[2] = 0.0f;   // loss_id
    }
}

extern "C" void kernel_launch(void* const* d_in, const int* in_sizes, int n_in,
                              void* d_out, int out_size, void* d_ws, size_t ws_size,
                              hipStream_t stream) {
    const float* feats = (const float*)d_in[0];  // (B,N,D) fp32
    const int* ids = (const int*)d_in[1];        // (B,N) int32
    float* out = (float*)d_out;                  // 3 fp32 scalars

    char* ws = (char*)d_ws;
    int2* desc = (int2*)ws;                                   // 256 KB
    int2* hdr = (int2*)(ws + sizeof(int2) * B * N);           // 512 B
    float* psum = (float*)(ws + sizeof(int2) * (B * N + B));  // 8 KB
    float* pcnt = psum + MB_BLOCKS;                           // 8 KB

    tl_tables<<<B, 512, 0, stream>>>(ids, desc, hdr);
    tl_main<<<MB_BLOCKS, MB_THREADS, 0, stream>>>(feats, desc, hdr, psum, pcnt);
    tl_finalize<<<1, 256, 0, stream>>>(psum, pcnt, out);
}